// Round 18
// baseline (743.998 us; speedup 1.0000x reference)
//
#include <hip/hip_runtime.h>
#include <math.h>

#define HID 64
#define ANNOT 512
#define NSTEPS 8
#define PCHUNK 4096
#define CSR_CAP 10240

typedef __attribute__((ext_vector_type(8))) short short8_t;
typedef __attribute__((ext_vector_type(16))) float floatx16;

__device__ __forceinline__ float sigmoidf_(float x) { return 1.0f / (1.0f + __expf(-x)); }

__device__ __forceinline__ float bf2f(unsigned short u) {
  return __uint_as_float(((unsigned)u) << 16);
}
__device__ __forceinline__ unsigned short f2bf(float f) {
  unsigned u = __float_as_uint(f);
  unsigned r = ((u >> 16) & 1u) + 0x7fffu;
  return (unsigned short)((u + r) >> 16);
}
__device__ __forceinline__ float bflo(unsigned u) { return __uint_as_float(u << 16); }
__device__ __forceinline__ float bfhi(unsigned u) { return __uint_as_float(u & 0xffff0000u); }
// HW packed f32x2 -> bf16x2 (single VOP3 instr, RNE)
__device__ __forceinline__ unsigned cvtpk_bf16(float lo, float hi) {
  unsigned r;
  asm("v_cvt_pk_bf16_f32 %0, %1, %2" : "=v"(r) : "v"(lo), "v"(hi));
  return r;
}

// ------------- Wpack: reduce_w (512x64 f32) -> bf16 MFMA B-fragments -------------
__global__ void k_wpack(const float* __restrict__ Wr, unsigned short* __restrict__ Wpack) {
  const int t = blockIdx.x;    // 0..63
  const int kc = t >> 1, nt = t & 1;
  const int l = threadIdx.x;   // 0..63
  const int c = nt * 32 + (l & 31);
  unsigned short* dst = Wpack + ((size_t)t * 64 + l) * 8;
#pragma unroll
  for (int j = 0; j < 8; ++j) {
    int k = kc * 16 + (l >> 5) * 8 + j;
    dst[j] = f2bf(Wr[(size_t)k * HID + c]);
  }
}

// ---------------- reduce: h[n,64] = x[n,512] @ Wr + br  (MFMA, no LDS; h bf16) ----------------
__global__ __launch_bounds__(256) void k_reduce(
    const float* __restrict__ x, const unsigned short* __restrict__ Wpack,
    const float* __restrict__ br, unsigned short* __restrict__ h, int n_nodes)
{
  const int wave = threadIdx.x >> 6;
  const int lane = threadIdx.x & 63;
  const int hi = lane >> 5;
  const int l31 = lane & 31;
  const int rbase = blockIdx.x * 128 + wave * 32;
  const int arow = rbase + l31;
  const bool avalid = arow < n_nodes;
  const float* xrow = x + (size_t)arow * ANNOT + hi * 8;

  floatx16 acc[2];
#pragma unroll
  for (int nt = 0; nt < 2; ++nt)
#pragma unroll
    for (int j = 0; j < 16; ++j) acc[nt][j] = 0.f;

#pragma unroll 4
  for (int kc = 0; kc < 32; ++kc) {
    short8_t a = {0, 0, 0, 0, 0, 0, 0, 0};
    if (avalid) {
      float4 u0 = *(const float4*)(xrow + kc * 16);
      float4 u1 = *(const float4*)(xrow + kc * 16 + 4);
      int4 ai;
      ai.x = (int)cvtpk_bf16(u0.x, u0.y);
      ai.y = (int)cvtpk_bf16(u0.z, u0.w);
      ai.z = (int)cvtpk_bf16(u1.x, u1.y);
      ai.w = (int)cvtpk_bf16(u1.z, u1.w);
      a = *(short8_t*)&ai;
    }
    const short8_t* Bb = (const short8_t*)(Wpack + (size_t)kc * 2 * 64 * 8);
#pragma unroll
    for (int nt = 0; nt < 2; ++nt) {
      short8_t b = Bb[nt * 64 + lane];
      acc[nt] = __builtin_amdgcn_mfma_f32_32x32x16_bf16(a, b, acc[nt], 0, 0, 0);
    }
  }

  float bias[2];
  bias[0] = br[l31];
  bias[1] = br[32 + l31];
#pragma unroll
  for (int reg = 0; reg < 16; ++reg) {
    int row = rbase + (reg & 3) + 8 * (reg >> 2) + 4 * hi;
    if (row < n_nodes) {
#pragma unroll
      for (int nt = 0; nt < 2; ++nt) {
        float v = acc[nt][reg] + bias[nt];
        h[(size_t)row * HID + nt * 32 + l31] = f2bf(v);
      }
    }
  }
}

// ------------- Bpack precompute: MFMA-fragment layout, bf16 -------------
__global__ void k_bbig(const float* __restrict__ ggc_w, const float* __restrict__ w_ih,
                       const float* __restrict__ w_hh, unsigned short* __restrict__ Bpack)
{
  const int nt = blockIdx.x;   // 0..7
  const int kc = blockIdx.y;   // 0..7
  const int s  = blockIdx.z;   // 0..7
  const int l  = threadIdx.x;  // 0..63
  const int c = nt * 32 + (l & 31);
  const int sec = c >> 6, f = c & 63;
  unsigned short outv[8];
#pragma unroll
  for (int j = 0; j < 8; ++j) {
    int k = kc * 16 + (l >> 5) * 8 + j;
    float v = 0.f;
    if (k < 64) {
      if (sec < 3) {
        const float* Ws = ggc_w + ((size_t)s * 64 + k) * 64;
        const float* wr = w_ih + (size_t)(sec * 64 + f) * 64;
        float a = 0.f;
        for (int q = 0; q < 64; ++q) a += Ws[q] * wr[q];
        v = a;
      }
    } else {
      int k2 = k - 64;
      if (sec == 0)      v = w_hh[(size_t)f * 64 + k2];
      else if (sec == 1) v = w_hh[(size_t)(64 + f) * 64 + k2];
      else if (sec == 3) v = w_hh[(size_t)(128 + f) * 64 + k2];
    }
    outv[j] = f2bf(v);
  }
  unsigned short* dst = Bpack + ((((size_t)s * 8 + kc) * 8 + nt) * 64 + l) * 8;
#pragma unroll
  for (int j = 0; j < 8; ++j) dst[j] = outv[j];
}

// ---------------- CSR build via bucket counting sort (packed uint records) ----------------
__global__ __launch_bounds__(256) void k_pcnt(const int* __restrict__ dstv, int E,
                                              int* __restrict__ bukCnt, int nbuk)
{
  __shared__ int lh[256];
  lh[threadIdx.x] = 0;
  __syncthreads();
  for (int e = blockIdx.x * blockDim.x + threadIdx.x; e < E; e += gridDim.x * blockDim.x)
    atomicAdd(&lh[dstv[e] >> 9], 1);
  __syncthreads();
  if (threadIdx.x < nbuk) {
    int v = lh[threadIdx.x];
    if (v) atomicAdd(&bukCnt[threadIdx.x], v);
  }
}

__global__ void k_bscan(const int* __restrict__ bukCnt, int nbuk,
                        int* __restrict__ bukBase, int* __restrict__ bukCur,
                        int* __restrict__ row_ptr, int n_nodes, int E)
{
  if (threadIdx.x == 0 && blockIdx.x == 0) {
    int run = 0;
    for (int b = 0; b < nbuk; ++b) { bukBase[b] = run; bukCur[b] = run; run += bukCnt[b]; }
    bukBase[nbuk] = run;
    row_ptr[n_nodes] = E;
  }
}

__global__ __launch_bounds__(256) void k_part(
    const int* __restrict__ srcv, const int* __restrict__ dstv, int E,
    int* __restrict__ bukCur, unsigned* __restrict__ rec, int nbuk)
{
  __shared__ int lhist[256], lexcl[256], lbase[256], lcur[256];
  __shared__ unsigned lrec[PCHUNK];
  __shared__ unsigned char lbuk[PCHUNK];
  const int t = threadIdx.x;
  const int nchunk = (E + PCHUNK - 1) / PCHUNK;
  for (int c = blockIdx.x; c < nchunk; c += gridDim.x) {
    const int e0 = c * PCHUNK;
    const int cnt = min(PCHUNK, E - e0);
    lhist[t] = 0;
    __syncthreads();
    int myS[16], myD[16];
#pragma unroll
    for (int i = 0; i < 16; ++i) {
      int j = t + i * 256;
      myS[i] = -1; myD[i] = 0;
      if (j < cnt) {
        int e = e0 + j;
        myS[i] = srcv[e];
        myD[i] = dstv[e];
        atomicAdd(&lhist[myD[i] >> 9], 1);
      }
    }
    __syncthreads();
    int v = lhist[t];
    lexcl[t] = v;
    __syncthreads();
    for (int d = 1; d < 256; d <<= 1) {
      int u = (t >= d) ? lexcl[t - d] : 0;
      __syncthreads();
      lexcl[t] += u;
      __syncthreads();
    }
    int excl = lexcl[t] - v;
    __syncthreads();
    lexcl[t] = excl;
    lcur[t] = excl;
    if (v > 0) lbase[t] = atomicAdd(&bukCur[t], v);
    __syncthreads();
#pragma unroll
    for (int i = 0; i < 16; ++i) {
      if (myS[i] >= 0) {
        int b = myD[i] >> 9;
        int p = atomicAdd(&lcur[b], 1);
        lrec[p] = (unsigned)myS[i] | ((unsigned)(myD[i] & 511) << 23);
        lbuk[p] = (unsigned char)b;
      }
    }
    __syncthreads();
    for (int j = t; j < cnt; j += 256) {
      int b = lbuk[j];
      rec[(size_t)lbase[b] + (j - lexcl[b])] = lrec[j];
    }
    __syncthreads();
  }
}

__global__ __launch_bounds__(512) void k_csr(
    const unsigned* __restrict__ rec, const int* __restrict__ bukBase,
    int* __restrict__ row_ptr, int* __restrict__ csr_src, int n_nodes)
{
  __shared__ int cnt[512], off[512], cur[512];
  __shared__ int outbuf[CSR_CAP];
  const int b = blockIdx.x;
  const int t = threadIdx.x;
  const int beg = bukBase[b], end = bukBase[b + 1];
  const int m = end - beg;
  const int node0 = b << 9;
  cnt[t] = 0;
  __syncthreads();
  for (int j = t; j < m; j += 512)
    atomicAdd(&cnt[rec[beg + j] >> 23], 1);
  __syncthreads();
  int v = cnt[t];
  off[t] = v;
  __syncthreads();
  for (int d = 1; d < 512; d <<= 1) {
    int u = (t >= d) ? off[t - d] : 0;
    __syncthreads();
    off[t] += u;
    __syncthreads();
  }
  int excl = off[t] - v;
  cur[t] = excl;
  int node = node0 + t;
  if (node < n_nodes) row_ptr[node] = beg + excl;
  __syncthreads();
  for (int j = t; j < m; j += 512) {
    unsigned r = rec[beg + j];
    int p = atomicAdd(&cur[r >> 23], 1);
    if (p < CSR_CAP) outbuf[p] = (int)(r & 0x7FFFFFu);
  }
  __syncthreads();
  for (int j = t; j < m; j += 512)
    csr_src[beg + j] = (j < CSR_CAP) ? outbuf[j] : 0;
}

// ---------------- per-step FUSED: gather-sum (LDS) + MFMA dual-GEMM + GRU ----------------
// Double-buffered h: reads h_in (gather + recurrent path), writes h_out. No cross-block race.
// Block = 4 waves = 128 nodes.
// Phase 1: 32 x 8-lane groups, each aggregates 4 nodes (continuous 4-deep pipeline) into
//          swizzled LDS rows (slot ^= row&7 kills the 128B-stride bank conflict).
// Phase 2: MFMA; A-fragments for K<64 from LDS, K>=64 from global h_in.
__global__ __launch_bounds__(256) void k_fused(
    const uint4* __restrict__ h16_in, const unsigned short* __restrict__ h_in,
    unsigned short* __restrict__ h_out,
    const int* __restrict__ row_ptr, const int* __restrict__ csr_src,
    const unsigned short* __restrict__ Bpack_s,
    const float* __restrict__ b_ih, const float* __restrict__ b_hh, int n_nodes)
{
  __shared__ uint4 albuf[128 * 8];   // 16 KB: [row][slot^(row&7)]
  const int tid = threadIdx.x;
  const int rbase = blockIdx.x * 128;

  // ---- Phase 1: aggregate 4 nodes per 8-lane group ----
  {
    const int g32 = tid >> 3;    // 0..31
    const int l8 = tid & 7;
#pragma unroll
    for (int i = 0; i < 4; ++i) {
      const int rl = g32 * 4 + i;           // local row 0..127
      const int n = rbase + rl;
      const bool valid = n < n_nodes;
      const int nc = valid ? n : (n_nodes - 1);
      const int beg = row_ptr[nc];
      const int end = valid ? row_ptr[nc + 1] : beg;
      const int last = end - 1;
      float a0 = 0.f, a1 = 0.f, a2 = 0.f, a3 = 0.f, a4 = 0.f, a5 = 0.f, a6 = 0.f, a7 = 0.f;

      for (int e = beg; e < end; e += 4) {
        int s0 = csr_src[min(e,     last)]; if (e     > last) s0 = n_nodes;
        int s1 = csr_src[min(e + 1, last)]; if (e + 1 > last) s1 = n_nodes;
        int s2 = csr_src[min(e + 2, last)]; if (e + 2 > last) s2 = n_nodes;
        int s3 = csr_src[min(e + 3, last)]; if (e + 3 > last) s3 = n_nodes;
        uint4 v0 = h16_in[(size_t)s0 * 8 + l8];
        uint4 v1 = h16_in[(size_t)s1 * 8 + l8];
        uint4 v2 = h16_in[(size_t)s2 * 8 + l8];
        uint4 v3 = h16_in[(size_t)s3 * 8 + l8];
        a0 += bflo(v0.x) + bflo(v1.x) + bflo(v2.x) + bflo(v3.x);
        a1 += bfhi(v0.x) + bfhi(v1.x) + bfhi(v2.x) + bfhi(v3.x);
        a2 += bflo(v0.y) + bflo(v1.y) + bflo(v2.y) + bflo(v3.y);
        a3 += bfhi(v0.y) + bfhi(v1.y) + bfhi(v2.y) + bfhi(v3.y);
        a4 += bflo(v0.z) + bflo(v1.z) + bflo(v2.z) + bflo(v3.z);
        a5 += bfhi(v0.z) + bfhi(v1.z) + bfhi(v2.z) + bfhi(v3.z);
        a6 += bflo(v0.w) + bflo(v1.w) + bflo(v2.w) + bflo(v3.w);
        a7 += bfhi(v0.w) + bfhi(v1.w) + bfhi(v2.w) + bfhi(v3.w);
      }
      uint4 o;
      o.x = cvtpk_bf16(a0, a1);
      o.y = cvtpk_bf16(a2, a3);
      o.z = cvtpk_bf16(a4, a5);
      o.w = cvtpk_bf16(a6, a7);
      albuf[rl * 8 + (l8 ^ (rl & 7))] = o;
    }
  }
  __syncthreads();

  // ---- Phase 2: MFMA + GRU ----
  const int wave = tid >> 6;
  const int lane = tid & 63;
  const int hi = lane >> 5;
  const int l31 = lane & 31;
  const int rl = wave * 32 + l31;      // local row for A reads
  const int arow = rbase + rl;
  const bool avalid = arow < n_nodes;

  floatx16 acc[8];
#pragma unroll
  for (int nt = 0; nt < 8; ++nt)
#pragma unroll
    for (int j = 0; j < 16; ++j) acc[nt][j] = 0.f;

#pragma unroll
  for (int kc = 0; kc < 8; ++kc) {
    short8_t a;
    if (kc < 4) {
      int slot = kc * 2 + hi;
      uint4 v = albuf[rl * 8 + (slot ^ (rl & 7))];
      a = *(short8_t*)&v;
    } else {
      short8_t az = {0, 0, 0, 0, 0, 0, 0, 0};
      a = az;
      if (avalid)
        a = *(const short8_t*)(h_in + (size_t)arow * HID + (kc & 3) * 16 + hi * 8);
    }
    const short8_t* Bb = (const short8_t*)(Bpack_s + (size_t)kc * 8 * 64 * 8);
#pragma unroll
    for (int nt = 0; nt < 8; ++nt) {
      short8_t b = Bb[nt * 64 + lane];
      acc[nt] = __builtin_amdgcn_mfma_f32_32x32x16_bf16(a, b, acc[nt], 0, 0, 0);
    }
  }

  float bi[2][3], bh[2][3];
#pragma unroll
  for (int half = 0; half < 2; ++half) {
    int f = half * 32 + l31;
    bi[half][0] = b_ih[f]; bi[half][1] = b_ih[64 + f]; bi[half][2] = b_ih[128 + f];
    bh[half][0] = b_hh[f]; bh[half][1] = b_hh[64 + f]; bh[half][2] = b_hh[128 + f];
  }
#pragma unroll
  for (int reg = 0; reg < 16; ++reg) {
    int row = rbase + wave * 32 + (reg & 3) + 8 * (reg >> 2) + 4 * hi;
    if (row < n_nodes) {
#pragma unroll
      for (int half = 0; half < 2; ++half) {
        int f = half * 32 + l31;
        float rg = sigmoidf_(acc[half][reg] + bi[half][0] + bh[half][0]);
        float zg = sigmoidf_(acc[2 + half][reg] + bi[half][1] + bh[half][1]);
        float ng = tanhf(acc[4 + half][reg] + bi[half][2] + rg * (acc[6 + half][reg] + bh[half][2]));
        size_t idx = (size_t)row * HID + f;
        float hold = bf2f(h_in[idx]);
        h_out[idx] = f2bf((1.f - zg) * ng + zg * hold);
      }
    }
  }
}

// ---------------- fused pooling: per-node gate/features + no-max-shift segment softmax sums ----------------
__global__ __launch_bounds__(256) void k_pool(
    const unsigned short* __restrict__ h, const int* __restrict__ batch,
    const float* __restrict__ gate_w, const float* __restrict__ gate_b,
    const float* __restrict__ out_w, const float* __restrict__ out_b,
    float* __restrict__ acc3, int n_nodes)
{
  __shared__ float sacc[192];
  int t = threadIdx.x;
  if (t < 192) sacc[t] = 0.f;
  __syncthreads();
  int n = blockIdx.x * blockDim.x + t;
  if (n < n_nodes) {
    float g = gate_b[0], f0 = out_b[0], f1 = out_b[1];
    const ushort4* hr = (const ushort4*)(h + (size_t)n * HID);
#pragma unroll
    for (int q = 0; q < 16; ++q) {
      ushort4 v = hr[q];
      float h0 = bf2f(v.x), h1 = bf2f(v.y), h2 = bf2f(v.z), h3 = bf2f(v.w);
      int k = q * 4;
      g += h0 * gate_w[k] + h1 * gate_w[k + 1] + h2 * gate_w[k + 2] + h3 * gate_w[k + 3];
      f0 += h0 * out_w[2 * k] + h1 * out_w[2 * k + 2] + h2 * out_w[2 * k + 4] + h3 * out_w[2 * k + 6];
      f1 += h0 * out_w[2 * k + 1] + h1 * out_w[2 * k + 3] + h2 * out_w[2 * k + 5] + h3 * out_w[2 * k + 7];
    }
    float e = expf(g);
    int b = batch[n];
    atomicAdd(&sacc[3 * b + 0], e);
    atomicAdd(&sacc[3 * b + 1], e * f0);
    atomicAdd(&sacc[3 * b + 2], e * f1);
  }
  __syncthreads();
  if (t < 192) {
    float v = sacc[t];
    if (v != 0.f) atomicAdd(&acc3[t], v);
  }
}

__global__ void k_pool3(const float* __restrict__ acc3, float* __restrict__ out, int n_graphs) {
  int g = blockIdx.x * blockDim.x + threadIdx.x;
  if (g < n_graphs) {
    float s = acc3[3 * g] + 1e-16f;
    float p0 = acc3[3 * g + 1] / s, p1 = acc3[3 * g + 2] / s;
    float m = fmaxf(p0, p1);
    float e0 = expf(p0 - m), e1 = expf(p1 - m);
    float d = e0 + e1;
    out[2 * g] = e0 / d;
    out[2 * g + 1] = e1 / d;
  }
}

// ---------------- host ----------------
extern "C" void kernel_launch(void* const* d_in, const int* in_sizes, int n_in,
                              void* d_out, int out_size, void* d_ws, size_t ws_size,
                              hipStream_t stream)
{
  const float* x        = (const float*)d_in[0];
  const int*   edge     = (const int*)d_in[1];
  const int*   batch    = (const int*)d_in[2];
  const float* reduce_w = (const float*)d_in[3];
  const float* reduce_b = (const float*)d_in[4];
  const float* ggc_w    = (const float*)d_in[5];
  const float* w_ih     = (const float*)d_in[6];
  const float* w_hh     = (const float*)d_in[7];
  const float* b_ih     = (const float*)d_in[8];
  const float* b_hh     = (const float*)d_in[9];
  const float* gate_w   = (const float*)d_in[10];
  const float* gate_b   = (const float*)d_in[11];
  const float* out_w    = (const float*)d_in[12];
  const float* out_b    = (const float*)d_in[13];
  float* out = (float*)d_out;

  const int n_nodes  = in_sizes[0] / ANNOT;
  const int E        = in_sizes[1] / 2;
  const int n_graphs = out_size / 2;
  const int* src  = edge;
  const int* dstv = edge + E;
  const int nbuk = (n_nodes + 511) >> 9;

  size_t off = 0;
  auto alloc = [&](size_t bytes) { size_t o = off; off = (off + bytes + 255) & ~(size_t)255; return o; };
  char* w = (char*)d_ws;

  unsigned short* hA   = (unsigned short*)(w + alloc((size_t)(n_nodes + 1) * HID * 2)); // +1 phantom zero row
  unsigned short* hB   = (unsigned short*)(w + alloc((size_t)(n_nodes + 1) * HID * 2));
  int*   csr_src = (int*)(w + alloc((size_t)E * 4));
  int*   row_ptr = (int*)(w + alloc((size_t)(n_nodes + 1) * 4));
  unsigned* rec  = (unsigned*)(w + alloc((size_t)E * 4));
  int*   bukCnt  = (int*)(w + alloc((size_t)(nbuk + 1) * 4));
  int*   bukBase = (int*)(w + alloc((size_t)(nbuk + 1) * 4));
  int*   bukCur  = (int*)(w + alloc((size_t)(nbuk + 1) * 4));
  unsigned short* Bpack = (unsigned short*)(w + alloc((size_t)NSTEPS * 8 * 8 * 64 * 8 * 2));
  unsigned short* Wpack = (unsigned short*)(w + alloc((size_t)64 * 64 * 8 * 2));
  float* acc3    = (float*)(w + alloc(192 * 4));
  (void)ws_size; (void)n_in;

  hipMemsetAsync(bukCnt, 0, (size_t)(nbuk + 1) * 4, stream);
  hipMemsetAsync(acc3, 0, 192 * 4, stream);
  hipMemsetAsync(hA + (size_t)n_nodes * HID, 0, HID * 2, stream);  // phantom zero rows
  hipMemsetAsync(hB + (size_t)n_nodes * HID, 0, HID * 2, stream);

  const int gN256 = (n_nodes + 255) / 256;
  const int nchunk = (E + PCHUNK - 1) / PCHUNK;

  k_wpack<<<64, 64, 0, stream>>>(reduce_w, Wpack);
  k_reduce<<<(n_nodes + 127) / 128, 256, 0, stream>>>(x, Wpack, reduce_b, hA, n_nodes);
  k_bbig<<<dim3(8, 8, NSTEPS), 64, 0, stream>>>(ggc_w, w_ih, w_hh, Bpack);

  k_pcnt<<<1024, 256, 0, stream>>>(dstv, E, bukCnt, nbuk);
  k_bscan<<<1, 1, 0, stream>>>(bukCnt, nbuk, bukBase, bukCur, row_ptr, n_nodes, E);
  k_part<<<nchunk, 256, 0, stream>>>(src, dstv, E, bukCur, rec, nbuk);
  k_csr<<<nbuk, 512, 0, stream>>>(rec, bukBase, row_ptr, csr_src, n_nodes);

  unsigned short* hin = hA;
  unsigned short* hout = hB;
  for (int s = 0; s < NSTEPS; ++s) {
    k_fused<<<(n_nodes + 127) / 128, 256, 0, stream>>>(
        (const uint4*)hin, hin, hout, row_ptr, csr_src,
        Bpack + (size_t)s * 8 * 8 * 64 * 8, b_ih, b_hh, n_nodes);
    unsigned short* tmp = hin; hin = hout; hout = tmp;
  }
  // after 8 steps (even), final h is back in hA (== hin)

  k_pool<<<gN256, 256, 0, stream>>>(hin, batch, gate_w, gate_b, out_w, out_b, acc3, n_nodes);
  k_pool3<<<1, 64, 0, stream>>>(acc3, out, n_graphs);
}

// Round 19
// 653.608 us; speedup vs baseline: 1.1383x; 1.1383x over previous
//
#include <hip/hip_runtime.h>
#include <math.h>

#define HID 64
#define ANNOT 512
#define NSTEPS 8
#define PCHUNK 4096
#define CSR_CAP 10240

typedef __attribute__((ext_vector_type(8))) short short8_t;
typedef __attribute__((ext_vector_type(16))) float floatx16;

__device__ __forceinline__ float sigmoidf_(float x) { return 1.0f / (1.0f + __expf(-x)); }

__device__ __forceinline__ float bf2f(unsigned short u) {
  return __uint_as_float(((unsigned)u) << 16);
}
__device__ __forceinline__ unsigned short f2bf(float f) {
  unsigned u = __float_as_uint(f);
  unsigned r = ((u >> 16) & 1u) + 0x7fffu;
  return (unsigned short)((u + r) >> 16);
}
__device__ __forceinline__ float bflo(unsigned u) { return __uint_as_float(u << 16); }
__device__ __forceinline__ float bfhi(unsigned u) { return __uint_as_float(u & 0xffff0000u); }
// HW packed f32x2 -> bf16x2 (single VOP3 instr, RNE)
__device__ __forceinline__ unsigned cvtpk_bf16(float lo, float hi) {
  unsigned r;
  asm("v_cvt_pk_bf16_f32 %0, %1, %2" : "=v"(r) : "v"(lo), "v"(hi));
  return r;
}

// ------------- Wpack: reduce_w (512x64 f32) -> bf16 MFMA B-fragments -------------
__global__ void k_wpack(const float* __restrict__ Wr, unsigned short* __restrict__ Wpack) {
  const int t = blockIdx.x;    // 0..63
  const int kc = t >> 1, nt = t & 1;
  const int l = threadIdx.x;   // 0..63
  const int c = nt * 32 + (l & 31);
  unsigned short* dst = Wpack + ((size_t)t * 64 + l) * 8;
#pragma unroll
  for (int j = 0; j < 8; ++j) {
    int k = kc * 16 + (l >> 5) * 8 + j;
    dst[j] = f2bf(Wr[(size_t)k * HID + c]);
  }
}

// ---------------- reduce: h[n,64] = x[n,512] @ Wr + br  (MFMA, no LDS; h bf16) ----------------
__global__ __launch_bounds__(256) void k_reduce(
    const float* __restrict__ x, const unsigned short* __restrict__ Wpack,
    const float* __restrict__ br, unsigned short* __restrict__ h, int n_nodes)
{
  const int wave = threadIdx.x >> 6;
  const int lane = threadIdx.x & 63;
  const int hi = lane >> 5;
  const int l31 = lane & 31;
  const int rbase = blockIdx.x * 128 + wave * 32;
  const int arow = rbase + l31;
  const bool avalid = arow < n_nodes;
  const float* xrow = x + (size_t)arow * ANNOT + hi * 8;

  floatx16 acc[2];
#pragma unroll
  for (int nt = 0; nt < 2; ++nt)
#pragma unroll
    for (int j = 0; j < 16; ++j) acc[nt][j] = 0.f;

#pragma unroll 4
  for (int kc = 0; kc < 32; ++kc) {
    short8_t a = {0, 0, 0, 0, 0, 0, 0, 0};
    if (avalid) {
      float4 u0 = *(const float4*)(xrow + kc * 16);
      float4 u1 = *(const float4*)(xrow + kc * 16 + 4);
      int4 ai;
      ai.x = (int)cvtpk_bf16(u0.x, u0.y);
      ai.y = (int)cvtpk_bf16(u0.z, u0.w);
      ai.z = (int)cvtpk_bf16(u1.x, u1.y);
      ai.w = (int)cvtpk_bf16(u1.z, u1.w);
      a = *(short8_t*)&ai;
    }
    const short8_t* Bb = (const short8_t*)(Wpack + (size_t)kc * 2 * 64 * 8);
#pragma unroll
    for (int nt = 0; nt < 2; ++nt) {
      short8_t b = Bb[nt * 64 + lane];
      acc[nt] = __builtin_amdgcn_mfma_f32_32x32x16_bf16(a, b, acc[nt], 0, 0, 0);
    }
  }

  float bias[2];
  bias[0] = br[l31];
  bias[1] = br[32 + l31];
#pragma unroll
  for (int reg = 0; reg < 16; ++reg) {
    int row = rbase + (reg & 3) + 8 * (reg >> 2) + 4 * hi;
    if (row < n_nodes) {
#pragma unroll
      for (int nt = 0; nt < 2; ++nt) {
        float v = acc[nt][reg] + bias[nt];
        h[(size_t)row * HID + nt * 32 + l31] = f2bf(v);
      }
    }
  }
}

// ------------- Bpack precompute: MFMA-fragment layout, bf16 -------------
__global__ void k_bbig(const float* __restrict__ ggc_w, const float* __restrict__ w_ih,
                       const float* __restrict__ w_hh, unsigned short* __restrict__ Bpack)
{
  const int nt = blockIdx.x;   // 0..7
  const int kc = blockIdx.y;   // 0..7
  const int s  = blockIdx.z;   // 0..7
  const int l  = threadIdx.x;  // 0..63
  const int c = nt * 32 + (l & 31);
  const int sec = c >> 6, f = c & 63;
  unsigned short outv[8];
#pragma unroll
  for (int j = 0; j < 8; ++j) {
    int k = kc * 16 + (l >> 5) * 8 + j;
    float v = 0.f;
    if (k < 64) {
      if (sec < 3) {
        const float* Ws = ggc_w + ((size_t)s * 64 + k) * 64;
        const float* wr = w_ih + (size_t)(sec * 64 + f) * 64;
        float a = 0.f;
        for (int q = 0; q < 64; ++q) a += Ws[q] * wr[q];
        v = a;
      }
    } else {
      int k2 = k - 64;
      if (sec == 0)      v = w_hh[(size_t)f * 64 + k2];
      else if (sec == 1) v = w_hh[(size_t)(64 + f) * 64 + k2];
      else if (sec == 3) v = w_hh[(size_t)(128 + f) * 64 + k2];
    }
    outv[j] = f2bf(v);
  }
  unsigned short* dst = Bpack + ((((size_t)s * 8 + kc) * 8 + nt) * 64 + l) * 8;
#pragma unroll
  for (int j = 0; j < 8; ++j) dst[j] = outv[j];
}

// ---------------- CSR build via bucket counting sort (packed uint records) ----------------
// record = src | (dst&511)<<23   (src < 2^23, bucket-local dst = 9 bits)
__global__ __launch_bounds__(256) void k_pcnt(const int* __restrict__ dstv, int E,
                                              int* __restrict__ bukCnt, int nbuk)
{
  __shared__ int lh[256];
  lh[threadIdx.x] = 0;
  __syncthreads();
  for (int e = blockIdx.x * blockDim.x + threadIdx.x; e < E; e += gridDim.x * blockDim.x)
    atomicAdd(&lh[dstv[e] >> 9], 1);
  __syncthreads();
  if (threadIdx.x < nbuk) {
    int v = lh[threadIdx.x];
    if (v) atomicAdd(&bukCnt[threadIdx.x], v);
  }
}

__global__ void k_bscan(const int* __restrict__ bukCnt, int nbuk,
                        int* __restrict__ bukBase, int* __restrict__ bukCur,
                        int* __restrict__ row_ptr, int n_nodes, int E)
{
  if (threadIdx.x == 0 && blockIdx.x == 0) {
    int run = 0;
    for (int b = 0; b < nbuk; ++b) { bukBase[b] = run; bukCur[b] = run; run += bukCnt[b]; }
    bukBase[nbuk] = run;
    row_ptr[n_nodes] = E;
  }
}

__global__ __launch_bounds__(256) void k_part(
    const int* __restrict__ srcv, const int* __restrict__ dstv, int E,
    int* __restrict__ bukCur, unsigned* __restrict__ rec, int nbuk)
{
  __shared__ int lhist[256], lexcl[256], lbase[256], lcur[256];
  __shared__ unsigned lrec[PCHUNK];
  __shared__ unsigned char lbuk[PCHUNK];
  const int t = threadIdx.x;
  const int nchunk = (E + PCHUNK - 1) / PCHUNK;
  for (int c = blockIdx.x; c < nchunk; c += gridDim.x) {
    const int e0 = c * PCHUNK;
    const int cnt = min(PCHUNK, E - e0);
    lhist[t] = 0;
    __syncthreads();
    int myS[16], myD[16];
#pragma unroll
    for (int i = 0; i < 16; ++i) {
      int j = t + i * 256;
      myS[i] = -1; myD[i] = 0;
      if (j < cnt) {
        int e = e0 + j;
        myS[i] = srcv[e];
        myD[i] = dstv[e];
        atomicAdd(&lhist[myD[i] >> 9], 1);
      }
    }
    __syncthreads();
    int v = lhist[t];
    lexcl[t] = v;
    __syncthreads();
    for (int d = 1; d < 256; d <<= 1) {
      int u = (t >= d) ? lexcl[t - d] : 0;
      __syncthreads();
      lexcl[t] += u;
      __syncthreads();
    }
    int excl = lexcl[t] - v;
    __syncthreads();
    lexcl[t] = excl;
    lcur[t] = excl;
    if (v > 0) lbase[t] = atomicAdd(&bukCur[t], v);
    __syncthreads();
#pragma unroll
    for (int i = 0; i < 16; ++i) {
      if (myS[i] >= 0) {
        int b = myD[i] >> 9;
        int p = atomicAdd(&lcur[b], 1);
        lrec[p] = (unsigned)myS[i] | ((unsigned)(myD[i] & 511) << 23);
        lbuk[p] = (unsigned char)b;
      }
    }
    __syncthreads();
    for (int j = t; j < cnt; j += 256) {
      int b = lbuk[j];
      rec[(size_t)lbase[b] + (j - lexcl[b])] = lrec[j];
    }
    __syncthreads();
  }
}

__global__ __launch_bounds__(512) void k_csr(
    const unsigned* __restrict__ rec, const int* __restrict__ bukBase,
    int* __restrict__ row_ptr, int* __restrict__ csr_src, int n_nodes)
{
  __shared__ int cnt[512], off[512], cur[512];
  __shared__ int outbuf[CSR_CAP];
  const int b = blockIdx.x;
  const int t = threadIdx.x;
  const int beg = bukBase[b], end = bukBase[b + 1];
  const int m = end - beg;
  const int node0 = b << 9;
  cnt[t] = 0;
  __syncthreads();
  for (int j = t; j < m; j += 512)
    atomicAdd(&cnt[rec[beg + j] >> 23], 1);
  __syncthreads();
  int v = cnt[t];
  off[t] = v;
  __syncthreads();
  for (int d = 1; d < 512; d <<= 1) {
    int u = (t >= d) ? off[t - d] : 0;
    __syncthreads();
    off[t] += u;
    __syncthreads();
  }
  int excl = off[t] - v;
  cur[t] = excl;
  int node = node0 + t;
  if (node < n_nodes) row_ptr[node] = beg + excl;
  __syncthreads();
  for (int j = t; j < m; j += 512) {
    unsigned r = rec[beg + j];
    int p = atomicAdd(&cur[r >> 23], 1);
    if (p < CSR_CAP) outbuf[p] = (int)(r & 0x7FFFFFu);
  }
  __syncthreads();
  for (int j = t; j < m; j += 512)
    csr_src[beg + j] = (j < CSR_CAP) ? outbuf[j] : 0;
}

// ---------------- per-step: CSR gather-sum of h (group-per-node, continuous 4-deep pipeline) ----------------
// 8-lane group <-> 1 node (8 nodes/wave, 32/block). Group walks its edge list 4 edges at a time;
// loads pipeline across iterations (loop dep only via accumulator). Finished groups are
// exec-masked off (no wasted slots). No cross-lane reduce: lane l8 owns features [8*l8, 8*l8+8).
// Tail slots clamp to the phantom zero row (index n_nodes, L1-hot).
__global__ __launch_bounds__(256) void k_aggr(
    const uint4* __restrict__ h16, const int* __restrict__ row_ptr,
    const int* __restrict__ csr_src, uint4* __restrict__ aggr16, int n_nodes)
{
  const int wid = threadIdx.x >> 6;
  const int lane = threadIdx.x & 63;
  const int grp = lane >> 3;
  const int l8 = lane & 7;
  const int n = blockIdx.x * 32 + wid * 8 + grp;
  const bool valid = n < n_nodes;
  const int nc = valid ? n : (n_nodes - 1);
  const int beg = row_ptr[nc];
  const int end = valid ? row_ptr[nc + 1] : beg;
  const int last = end - 1;
  float a0 = 0.f, a1 = 0.f, a2 = 0.f, a3 = 0.f, a4 = 0.f, a5 = 0.f, a6 = 0.f, a7 = 0.f;

  for (int e = beg; e < end; e += 4) {
    int s0 = csr_src[min(e,     last)]; if (e     > last) s0 = n_nodes;
    int s1 = csr_src[min(e + 1, last)]; if (e + 1 > last) s1 = n_nodes;
    int s2 = csr_src[min(e + 2, last)]; if (e + 2 > last) s2 = n_nodes;
    int s3 = csr_src[min(e + 3, last)]; if (e + 3 > last) s3 = n_nodes;
    uint4 v0 = h16[(size_t)s0 * 8 + l8];
    uint4 v1 = h16[(size_t)s1 * 8 + l8];
    uint4 v2 = h16[(size_t)s2 * 8 + l8];
    uint4 v3 = h16[(size_t)s3 * 8 + l8];
    a0 += bflo(v0.x) + bflo(v1.x) + bflo(v2.x) + bflo(v3.x);
    a1 += bfhi(v0.x) + bfhi(v1.x) + bfhi(v2.x) + bfhi(v3.x);
    a2 += bflo(v0.y) + bflo(v1.y) + bflo(v2.y) + bflo(v3.y);
    a3 += bfhi(v0.y) + bfhi(v1.y) + bfhi(v2.y) + bfhi(v3.y);
    a4 += bflo(v0.z) + bflo(v1.z) + bflo(v2.z) + bflo(v3.z);
    a5 += bfhi(v0.z) + bfhi(v1.z) + bfhi(v2.z) + bfhi(v3.z);
    a6 += bflo(v0.w) + bflo(v1.w) + bflo(v2.w) + bflo(v3.w);
    a7 += bfhi(v0.w) + bfhi(v1.w) + bfhi(v2.w) + bfhi(v3.w);
  }

  if (valid) {
    uint4 o;
    o.x = cvtpk_bf16(a0, a1);
    o.y = cvtpk_bf16(a2, a3);
    o.z = cvtpk_bf16(a4, a5);
    o.w = cvtpk_bf16(a6, a7);
    aggr16[(size_t)n * 8 + l8] = o;
  }
}

// ---------------- per-step: MFMA dual-GEMM + GRU gates (in-place bf16 h update) ----------------
__global__ __launch_bounds__(256) void k_gru(
    const unsigned short* __restrict__ aggr, unsigned short* __restrict__ h,
    const unsigned short* __restrict__ Bpack_s,
    const float* __restrict__ b_ih, const float* __restrict__ b_hh, int n_nodes)
{
  const int wave = threadIdx.x >> 6;
  const int lane = threadIdx.x & 63;
  const int hi = lane >> 5;
  const int l31 = lane & 31;
  const int rbase = blockIdx.x * 128 + wave * 32;
  const int arow = rbase + l31;
  const bool avalid = arow < n_nodes;

  floatx16 acc[8];
#pragma unroll
  for (int nt = 0; nt < 8; ++nt)
#pragma unroll
    for (int j = 0; j < 16; ++j) acc[nt][j] = 0.f;

#pragma unroll
  for (int kc = 0; kc < 8; ++kc) {
    const unsigned short* Asrc = (kc < 4) ? aggr : h;
    short8_t a = {0, 0, 0, 0, 0, 0, 0, 0};
    if (avalid)
      a = *(const short8_t*)(Asrc + (size_t)arow * HID + (kc & 3) * 16 + hi * 8);
    const short8_t* Bb = (const short8_t*)(Bpack_s + (size_t)kc * 8 * 64 * 8);
#pragma unroll
    for (int nt = 0; nt < 8; ++nt) {
      short8_t b = Bb[nt * 64 + lane];
      acc[nt] = __builtin_amdgcn_mfma_f32_32x32x16_bf16(a, b, acc[nt], 0, 0, 0);
    }
  }

  float bi[2][3], bh[2][3];
#pragma unroll
  for (int half = 0; half < 2; ++half) {
    int f = half * 32 + l31;
    bi[half][0] = b_ih[f]; bi[half][1] = b_ih[64 + f]; bi[half][2] = b_ih[128 + f];
    bh[half][0] = b_hh[f]; bh[half][1] = b_hh[64 + f]; bh[half][2] = b_hh[128 + f];
  }
#pragma unroll
  for (int reg = 0; reg < 16; ++reg) {
    int row = rbase + (reg & 3) + 8 * (reg >> 2) + 4 * hi;
    if (row < n_nodes) {
#pragma unroll
      for (int half = 0; half < 2; ++half) {
        int f = half * 32 + l31;
        float rg = sigmoidf_(acc[half][reg] + bi[half][0] + bh[half][0]);
        float zg = sigmoidf_(acc[2 + half][reg] + bi[half][1] + bh[half][1]);
        float ng = tanhf(acc[4 + half][reg] + bi[half][2] + rg * (acc[6 + half][reg] + bh[half][2]));
        size_t idx = (size_t)row * HID + f;
        float hold = bf2f(h[idx]);
        h[idx] = f2bf((1.f - zg) * ng + zg * hold);
      }
    }
  }
}

// ---------------- fused pooling: per-node gate/features + no-max-shift segment softmax sums ----------------
__global__ __launch_bounds__(256) void k_pool(
    const unsigned short* __restrict__ h, const int* __restrict__ batch,
    const float* __restrict__ gate_w, const float* __restrict__ gate_b,
    const float* __restrict__ out_w, const float* __restrict__ out_b,
    float* __restrict__ acc3, int n_nodes)
{
  __shared__ float sacc[192];
  int t = threadIdx.x;
  if (t < 192) sacc[t] = 0.f;
  __syncthreads();
  int n = blockIdx.x * blockDim.x + t;
  if (n < n_nodes) {
    float g = gate_b[0], f0 = out_b[0], f1 = out_b[1];
    const ushort4* hr = (const ushort4*)(h + (size_t)n * HID);
#pragma unroll
    for (int q = 0; q < 16; ++q) {
      ushort4 v = hr[q];
      float h0 = bf2f(v.x), h1 = bf2f(v.y), h2 = bf2f(v.z), h3 = bf2f(v.w);
      int k = q * 4;
      g += h0 * gate_w[k] + h1 * gate_w[k + 1] + h2 * gate_w[k + 2] + h3 * gate_w[k + 3];
      f0 += h0 * out_w[2 * k] + h1 * out_w[2 * k + 2] + h2 * out_w[2 * k + 4] + h3 * out_w[2 * k + 6];
      f1 += h0 * out_w[2 * k + 1] + h1 * out_w[2 * k + 3] + h2 * out_w[2 * k + 5] + h3 * out_w[2 * k + 7];
    }
    float e = expf(g);
    int b = batch[n];
    atomicAdd(&sacc[3 * b + 0], e);
    atomicAdd(&sacc[3 * b + 1], e * f0);
    atomicAdd(&sacc[3 * b + 2], e * f1);
  }
  __syncthreads();
  if (t < 192) {
    float v = sacc[t];
    if (v != 0.f) atomicAdd(&acc3[t], v);
  }
}

__global__ void k_pool3(const float* __restrict__ acc3, float* __restrict__ out, int n_graphs) {
  int g = blockIdx.x * blockDim.x + threadIdx.x;
  if (g < n_graphs) {
    float s = acc3[3 * g] + 1e-16f;
    float p0 = acc3[3 * g + 1] / s, p1 = acc3[3 * g + 2] / s;
    float m = fmaxf(p0, p1);
    float e0 = expf(p0 - m), e1 = expf(p1 - m);
    float d = e0 + e1;
    out[2 * g] = e0 / d;
    out[2 * g + 1] = e1 / d;
  }
}

// ---------------- host ----------------
extern "C" void kernel_launch(void* const* d_in, const int* in_sizes, int n_in,
                              void* d_out, int out_size, void* d_ws, size_t ws_size,
                              hipStream_t stream)
{
  const float* x        = (const float*)d_in[0];
  const int*   edge     = (const int*)d_in[1];
  const int*   batch    = (const int*)d_in[2];
  const float* reduce_w = (const float*)d_in[3];
  const float* reduce_b = (const float*)d_in[4];
  const float* ggc_w    = (const float*)d_in[5];
  const float* w_ih     = (const float*)d_in[6];
  const float* w_hh     = (const float*)d_in[7];
  const float* b_ih     = (const float*)d_in[8];
  const float* b_hh     = (const float*)d_in[9];
  const float* gate_w   = (const float*)d_in[10];
  const float* gate_b   = (const float*)d_in[11];
  const float* out_w    = (const float*)d_in[12];
  const float* out_b    = (const float*)d_in[13];
  float* out = (float*)d_out;

  const int n_nodes  = in_sizes[0] / ANNOT;
  const int E        = in_sizes[1] / 2;
  const int n_graphs = out_size / 2;
  const int* src  = edge;
  const int* dstv = edge + E;
  const int nbuk = (n_nodes + 511) >> 9;

  size_t off = 0;
  auto alloc = [&](size_t bytes) { size_t o = off; off = (off + bytes + 255) & ~(size_t)255; return o; };
  char* w = (char*)d_ws;

  unsigned short* h    = (unsigned short*)(w + alloc((size_t)(n_nodes + 1) * HID * 2)); // +1 phantom zero row
  unsigned short* aggr = (unsigned short*)(w + alloc((size_t)n_nodes * HID * 2));
  int*   csr_src = (int*)(w + alloc((size_t)E * 4));
  int*   row_ptr = (int*)(w + alloc((size_t)(n_nodes + 1) * 4));
  unsigned* rec  = (unsigned*)(w + alloc((size_t)E * 4));
  int*   bukCnt  = (int*)(w + alloc((size_t)(nbuk + 1) * 4));
  int*   bukBase = (int*)(w + alloc((size_t)(nbuk + 1) * 4));
  int*   bukCur  = (int*)(w + alloc((size_t)(nbuk + 1) * 4));
  unsigned short* Bpack = (unsigned short*)(w + alloc((size_t)NSTEPS * 8 * 8 * 64 * 8 * 2));
  unsigned short* Wpack = (unsigned short*)(w + alloc((size_t)64 * 64 * 8 * 2));
  float* acc3    = (float*)(w + alloc(192 * 4));
  (void)ws_size; (void)n_in;

  hipMemsetAsync(bukCnt, 0, (size_t)(nbuk + 1) * 4, stream);
  hipMemsetAsync(acc3, 0, 192 * 4, stream);
  hipMemsetAsync(h + (size_t)n_nodes * HID, 0, HID * 2, stream);  // phantom zero row

  const int gN256 = (n_nodes + 255) / 256;
  const int nchunk = (E + PCHUNK - 1) / PCHUNK;

  k_wpack<<<64, 64, 0, stream>>>(reduce_w, Wpack);
  k_reduce<<<(n_nodes + 127) / 128, 256, 0, stream>>>(x, Wpack, reduce_b, h, n_nodes);
  k_bbig<<<dim3(8, 8, NSTEPS), 64, 0, stream>>>(ggc_w, w_ih, w_hh, Bpack);

  k_pcnt<<<1024, 256, 0, stream>>>(dstv, E, bukCnt, nbuk);
  k_bscan<<<1, 1, 0, stream>>>(bukCnt, nbuk, bukBase, bukCur, row_ptr, n_nodes, E);
  k_part<<<nchunk, 256, 0, stream>>>(src, dstv, E, bukCur, rec, nbuk);
  k_csr<<<nbuk, 512, 0, stream>>>(rec, bukBase, row_ptr, csr_src, n_nodes);

  for (int s = 0; s < NSTEPS; ++s) {
    k_aggr<<<(n_nodes + 31) / 32, 256, 0, stream>>>((const uint4*)h, row_ptr, csr_src, (uint4*)aggr, n_nodes);
    k_gru<<<(n_nodes + 127) / 128, 256, 0, stream>>>(aggr, h, Bpack + (size_t)s * 8 * 8 * 64 * 8, b_ih, b_hh, n_nodes);
  }

  k_pool<<<gN256, 256, 0, stream>>>(h, batch, gate_w, gate_b, out_w, out_b, acc3, n_nodes);
  k_pool3<<<1, 64, 0, stream>>>(acc3, out, n_graphs);
}